// Round 10
// baseline (55.067 us; speedup 1.0000x reference)
//
#include <hip/hip_runtime.h>
#include <hip/hip_bf16.h>

typedef float f32x4 __attribute__((ext_vector_type(4)));
typedef _Float16 f16x2 __attribute__((ext_vector_type(2)));
typedef _Float16 f16x8 __attribute__((ext_vector_type(8)));

#define CC   64
#define HID  256
#define NOUT 64
#define HOUT 384
#define MAXCELL 16                // 16-row x 16-col tile: <=4 cell-rows x 4 cell-cols
#define CELLB 544                 // 512 data + 32 pad
#define UVB  (MAXCELL * CELLB)    // 8704
#define W2B  (UVB + 1024)         // 9728
#define SMEMB (W2B + 32768)       // 42496 B -> 3 blocks/CU

// ---- k_prep: w2 -> W2F frags, w1[0:64] -> W1F frags, w1[64:66] -> UVH f16
__global__ __launch_bounds__(256) void k_prep(const float* __restrict__ w1,
                                              const float* __restrict__ w2,
                                              _Float16* __restrict__ W2F,
                                              _Float16* __restrict__ W1F,
                                              _Float16* __restrict__ UVH) {
    int idx = blockIdx.x * 256 + threadIdx.x;
    if (idx < 16384) {
        int f = idx, e = f & 7, l = (f >> 3) & 63, grp = f >> 9;
        int ks = grp >> 2, ng = grp & 3;
        int k = ks * 32 + ((l >> 4) << 3) + e;
        int n = (ng << 4) + (l & 15);
        W2F[f] = (_Float16)w2[k * NOUT + n];
    } else if (idx < 32768) {
        int f = idx - 16384, e = f & 7, l = (f >> 3) & 63, grp = f >> 9;
        int ks = grp >> 4, ng = grp & 15;
        int k = ks * 32 + ((l >> 4) << 3) + e;
        int n = (ng << 4) + (l & 15);
        W1F[f] = (_Float16)w1[k * HID + n];
    } else if (idx < 32768 + 512) {
        int f = idx - 32768;
        UVH[f] = (_Float16)w1[(CC + (f >> 8)) * HID + (f & 255)];
    }
}

// ---- k_gfeat (MFMA): G[cell][n] = b1[n] + sum_c res_f16[cell][c] * w1_f16[c][n]
__global__ __launch_bounds__(256) void k_gfeat(const float* __restrict__ res,
                                               const _Float16* __restrict__ W1F,
                                               const float* __restrict__ b1,
                                               _Float16* __restrict__ G) {
    const int cell0 = blockIdx.x * 32;
    const int b = cell0 >> 12, iyix0 = cell0 & 4095;
    const int tid = threadIdx.x;
    __shared__ _Float16 lds_a[32][72];
    __shared__ _Float16 lds_d[32][264];
    {
        int c = tid >> 2, cs = (tid & 3) * 8;
        const float* src = res + (((b * CC + c) << 12) + iyix0 + cs);
        f32x4 r0 = *(const f32x4*)src;
        f32x4 r1 = *(const f32x4*)(src + 4);
#pragma unroll
        for (int e = 0; e < 4; ++e) lds_a[cs + e][c] = (_Float16)r0[e];
#pragma unroll
        for (int e = 0; e < 4; ++e) lds_a[cs + 4 + e][c] = (_Float16)r1[e];
    }
    __syncthreads();
    const int wv = tid >> 6, l = tid & 63, lhi = l >> 4, dj = l & 15;
    const int crow = (wv & 1) * 16;
    const int nh = (wv >> 1) * 8;
    f32x4 acc[8];
#pragma unroll
    for (int q = 0; q < 8; ++q) {
        float bb = b1[(nh + q) * 16 + dj];
        acc[q] = (f32x4){bb, bb, bb, bb};
    }
#pragma unroll
    for (int ks = 0; ks < 2; ++ks) {
        f16x8 afr = *(const f16x8*)&lds_a[crow + dj][ks * 32 + lhi * 8];
#pragma unroll
        for (int q = 0; q < 8; ++q) {
            f16x8 bfr = *(const f16x8*)(W1F + (((ks * 16 + nh + q) * 64 + l) << 3));
            acc[q] = __builtin_amdgcn_mfma_f32_16x16x32_f16(afr, bfr, acc[q], 0, 0, 0);
        }
    }
#pragma unroll
    for (int q = 0; q < 8; ++q) {
        int n = (nh + q) * 16 + dj;
#pragma unroll
        for (int r = 0; r < 4; ++r)
            lds_d[crow + lhi * 4 + r][n] = (_Float16)acc[q][r];
    }
    __syncthreads();
    {
        int cell = tid >> 3, ch = (tid & 7) * 32;
        _Float16* dst = G + (((size_t)(cell0 + cell)) << 8) + ch;
#pragma unroll
        for (int r = 0; r < 4; ++r)
            *(f32x4*)(dst + r * 8) = *(const f32x4*)&lds_d[cell][ch + r * 8];
    }
}

// ---- main: block = 4 waves, tile = 16 rows x 16 cols; wave = 4 adjacent rows.
// Rows of a wave fall in <=2 cell-rows (3 uniform cases mod 12): one gvA
// (+cond gvB) read pair serves all 4 strips. ks-outer: uv+w2 read once per ks
// for 64 px. Integer corner math.
__global__ __launch_bounds__(256, 3) void k_main(const _Float16* __restrict__ G,
                                                 const _Float16* __restrict__ W2F,
                                                 const _Float16* __restrict__ UVH,
                                                 const float* __restrict__ b2,
                                                 float* __restrict__ out) {
    const int jt = blockIdx.x;        // 0..23
    const int it = blockIdx.y;        // 0..23
    const int b  = blockIdx.z;        // 0..1
    const int tid = threadIdx.x;
    const int wv = tid >> 6, l = tid & 63;
    const int lhi = l >> 4, dj = l & 15;
    const int i0 = it * 16, j0 = jt * 16;

    __shared__ char smem[SMEMB];

    // ---- integer staged-cell bounds
    const int r0 = i0 / 6;
    const int i15 = i0 + 15, ci15 = i15 / 6;
    const int r1 = min(ci15 + ((i15 - 6 * ci15) == 5 ? 1 : 0), 63);
    const int c0 = j0 / 6;
    const int j15 = j0 + 15, cj15 = j15 / 6;
    const int c1 = min(cj15 + ((j15 - 6 * cj15) == 5 ? 1 : 0), 63);
    const int ncc = c1 - c0 + 1;              // 3 or 4
    const int ncell = (r1 - r0 + 1) * ncc;    // <= 16

    // ---- stage: cells (f16), uv, W2F
    for (int t = tid; t < (ncell << 5); t += 256) {
        int cl = t >> 5, c16 = t & 31;
        int cr = (ncc == 4) ? (cl >> 2) : ((cl * 11) >> 5);
        int cc = cl - cr * ncc;
        const _Float16* src = G + (((size_t)((b << 12) + ((r0 + cr) << 6) + (c0 + cc))) << 8) + (c16 << 3);
        *(f32x4*)(smem + cl * CELLB + (c16 << 4)) = *(const f32x4*)src;
    }
    if (tid < 64)
        *(f32x4*)(smem + UVB + (tid << 4)) = *(const f32x4*)(UVH + (tid << 3));
    {
        const f32x4* w2g = (const f32x4*)W2F;
#pragma unroll
        for (int t = 0; t < 8; ++t)
            *(f32x4*)(smem + W2B + ((t * 256 + tid) << 4)) = w2g[t * 256 + tid];
    }
    float bbv[4];
#pragma unroll
    for (int ng = 0; ng < 4; ++ng) bbv[ng] = b2[(ng << 4) + dj];
    __syncthreads();

    // ---- x setup (per lane)
    const int j = j0 + dj;
    const int cj = j / 6, pj = j - 6 * cj;
    const bool xs = (pj == 5) && (cj < 63);
    const float rx0 = (float)(2 * pj - 5) * (1.f / 6.f);
    const float rx1 = xs ? rx0 - 2.f : rx0;

    // ---- y setup: wave rows ia..ia+3; case id = (ia mod 12)/4
    const int ia = i0 + (wv << 2);
    const int cid = (ia >> 2) % 3;
    const int ciA = ia / 6, rA = ciA - r0;

    // generic per-row params (wave-uniform ints, per-lane weights)
#define DUP2(x) (f16x2){(_Float16)(x), (_Float16)(x)}
    f16x2 ryh[4], rysh[4], W00h[4], W01h[4], W10h[4], W11h[4];
#pragma unroll
    for (int p = 0; p < 4; ++p) {
        const int ip = ia + p;
        const int cip = ip / 6, pip = ip - 6 * cip;
        const float ry0 = (float)(2 * pip - 5) * (1.f / 6.f);
        const bool ys = (pip == 5) && (cip < 63);
        const float ry1 = ys ? ry0 - 2.f : ry0;
        const float a00 = fabsf(ry0 * rx0) + 1e-9f;
        const float a01 = fabsf(ry0 * rx1) + 1e-9f;
        const float a10 = fabsf(ry1 * rx0) + 1e-9f;
        const float a11 = fabsf(ry1 * rx1) + 1e-9f;
        const float inv = 1.f / (a00 + a01 + a10 + a11);
        float w00 = a11, w01 = 0.f, w10 = 0.f, w11 = 0.f;
        if (xs) w01 += a10; else w00 += a10;
        if (ys) w10 += a01; else w00 += a01;
        if (ys && xs) w11 += a00;
        else if (ys)  w10 += a00;
        else if (xs)  w01 += a00;
        else          w00 += a00;
        ryh[p] = DUP2(ry0); rysh[p] = DUP2(ry1);
        W00h[p] = DUP2(w00 * inv); W01h[p] = DUP2(w01 * inv);
        W10h[p] = DUP2(w10 * inv); W11h[p] = DUP2(w11 * inv);
    }
    const f16x2 rx0h = DUP2(rx0), rx1h = DUP2(rx1);
    const f16x2 zeroh = DUP2(0.f);
    const bool ys3 = (cid == 2) && ((ia + 3) < 378);   // case2 split row valid

    const int lo16 = lhi << 4;
    const int cm = cj - c0, cp = cm + (xs ? 1 : 0);
    const char* cA0 = smem + (rA * ncc + cm) * CELLB + lo16;
    const char* cA1 = smem + (rA * ncc + cp) * CELLB + lo16;
    const char* cB0 = cA0 + ncc * CELLB;
    const char* cB1 = cA1 + ncc * CELLB;
    const char* uvp = smem + UVB + lo16;
    const f16x8* w2l = (const f16x8*)(smem + W2B) + l;

    f32x4 acc[4][4];
#pragma unroll
    for (int p = 0; p < 4; ++p)
#pragma unroll
        for (int ng = 0; ng < 4; ++ng) acc[p][ng] = (f32x4){0.f, 0.f, 0.f, 0.f};

#define KS_HEAD                                                              \
        const int ko = ks * 64;                                              \
        f16x8 uraw = *(const f16x8*)(uvp + ko);                              \
        f16x8 vraw = *(const f16x8*)(uvp + 512 + ko);                        \
        const f16x2* uu = (const f16x2*)&uraw;                               \
        const f16x2* vv = (const f16x2*)&vraw;                               \
        f16x8 bfr[4];                                                        \
        _Pragma("unroll")                                                    \
        for (int ng = 0; ng < 4; ++ng) bfr[ng] = w2l[(ks * 4 + ng) * 64];

#define ROW_BASE(P, G0V, G1V)                                                \
        _Pragma("unroll")                                                    \
        for (int e = 0; e < 4; ++e) {                                        \
            f16x2 t0 = ((const f16x2*)&(G0V))[e] + ryh[P] * uu[e] + rx0h * vv[e]; \
            f16x2 t1 = ((const f16x2*)&(G1V))[e] + ryh[P] * uu[e] + rx1h * vv[e]; \
            t0 = __builtin_elementwise_max(t0, zeroh);                       \
            t1 = __builtin_elementwise_max(t1, zeroh);                       \
            hh[e] = W00h[P] * t0 + W01h[P] * t1;                             \
        }

#define ROW_SPLIT(P, G0V, G1V)                                               \
        _Pragma("unroll")                                                    \
        for (int e = 0; e < 4; ++e) {                                        \
            f16x2 s0 = ((const f16x2*)&(G0V))[e] + rysh[P] * uu[e] + rx0h * vv[e]; \
            f16x2 s1 = ((const f16x2*)&(G1V))[e] + rysh[P] * uu[e] + rx1h * vv[e]; \
            s0 = __builtin_elementwise_max(s0, zeroh);                       \
            s1 = __builtin_elementwise_max(s1, zeroh);                       \
            hh[e] += W10h[P] * s0 + W11h[P] * s1;                            \
        }

#define ROW_MFMA(P)                                                          \
        _Pragma("unroll")                                                    \
        for (int ng = 0; ng < 4; ++ng)                                       \
            acc[P][ng] = __builtin_amdgcn_mfma_f32_16x16x32_f16(hv, bfr[ng], acc[P][ng], 0, 0, 0);

    if (cid == 0) {               // rows pi 0..3: all cell-row A, no splits
#pragma unroll
        for (int ks = 0; ks < 8; ++ks) {
            KS_HEAD
            f16x8 gA0 = *(const f16x8*)(cA0 + ko);
            f16x8 gA1 = *(const f16x8*)(cA1 + ko);
            { f16x8 hv; f16x2* hh = (f16x2*)&hv; ROW_BASE(0, gA0, gA1) ROW_MFMA(0) }
            { f16x8 hv; f16x2* hh = (f16x2*)&hv; ROW_BASE(1, gA0, gA1) ROW_MFMA(1) }
            { f16x8 hv; f16x2* hh = (f16x2*)&hv; ROW_BASE(2, gA0, gA1) ROW_MFMA(2) }
            { f16x8 hv; f16x2* hh = (f16x2*)&hv; ROW_BASE(3, gA0, gA1) ROW_MFMA(3) }
        }
    } else if (cid == 1) {        // rows pi 4,5,0,1: A,A(split->B),B,B
#pragma unroll
        for (int ks = 0; ks < 8; ++ks) {
            KS_HEAD
            f16x8 gA0 = *(const f16x8*)(cA0 + ko);
            f16x8 gA1 = *(const f16x8*)(cA1 + ko);
            f16x8 gB0 = *(const f16x8*)(cB0 + ko);
            f16x8 gB1 = *(const f16x8*)(cB1 + ko);
            { f16x8 hv; f16x2* hh = (f16x2*)&hv; ROW_BASE(0, gA0, gA1) ROW_MFMA(0) }
            { f16x8 hv; f16x2* hh = (f16x2*)&hv; ROW_BASE(1, gA0, gA1) ROW_SPLIT(1, gB0, gB1) ROW_MFMA(1) }
            { f16x8 hv; f16x2* hh = (f16x2*)&hv; ROW_BASE(2, gB0, gB1) ROW_MFMA(2) }
            { f16x8 hv; f16x2* hh = (f16x2*)&hv; ROW_BASE(3, gB0, gB1) ROW_MFMA(3) }
        }
    } else {                      // rows pi 2,3,4,5: all A, row3 split->B (cond)
#pragma unroll
        for (int ks = 0; ks < 8; ++ks) {
            KS_HEAD
            f16x8 gA0 = *(const f16x8*)(cA0 + ko);
            f16x8 gA1 = *(const f16x8*)(cA1 + ko);
            { f16x8 hv; f16x2* hh = (f16x2*)&hv; ROW_BASE(0, gA0, gA1) ROW_MFMA(0) }
            { f16x8 hv; f16x2* hh = (f16x2*)&hv; ROW_BASE(1, gA0, gA1) ROW_MFMA(1) }
            { f16x8 hv; f16x2* hh = (f16x2*)&hv; ROW_BASE(2, gA0, gA1) ROW_MFMA(2) }
            { f16x8 hv; f16x2* hh = (f16x2*)&hv; ROW_BASE(3, gA0, gA1)
              if (ys3) {
                  f16x8 gB0 = *(const f16x8*)(cB0 + ko);
                  f16x8 gB1 = *(const f16x8*)(cB1 + ko);
                  ROW_SPLIT(3, gB0, gB1)
              }
              ROW_MFMA(3) }
        }
    }
#undef KS_HEAD
#undef ROW_BASE
#undef ROW_SPLIT
#undef ROW_MFMA

    // ---- epilogue: direct stores (D row = px col j0+lhi*4+r, D col = channel)
#pragma unroll
    for (int p = 0; p < 4; ++p) {
        const int irow = ia + p;
#pragma unroll
        for (int ng = 0; ng < 4; ++ng) {
            const int o = (ng << 4) + dj;
            float* op = out + (((size_t)b * NOUT + o) * HOUT + irow) * HOUT + j0 + (lhi << 2);
#pragma unroll
            for (int r = 0; r < 4; ++r)
                op[r] = acc[p][ng][r] + bbv[ng];
        }
    }
}

extern "C" void kernel_launch(void* const* d_in, const int* in_sizes, int n_in,
                              void* d_out, int out_size, void* d_ws, size_t ws_size,
                              hipStream_t stream) {
    const float* res = (const float*)d_in[0];
    const float* w1  = (const float*)d_in[1];
    const float* b1  = (const float*)d_in[2];
    const float* w2  = (const float*)d_in[3];
    const float* b2  = (const float*)d_in[4];
    float* out = (float*)d_out;

    char* ws = (char*)d_ws;
    _Float16* G   = (_Float16*)ws;                              // 4 MB
    _Float16* W2F = (_Float16*)(ws + (size_t)(8u << 20));       // 32 KB
    _Float16* W1F = (_Float16*)(ws + (size_t)(8u << 20) + 65536);
    _Float16* UVH = (_Float16*)(ws + (size_t)(8u << 20) + 131072);

    k_prep<<<130, 256, 0, stream>>>(w1, w2, W2F, W1F, UVH);
    k_gfeat<<<256, 256, 0, stream>>>(res, W1F, b1, G);
    k_main<<<dim3(24, 24, 2), 256, 0, stream>>>(G, W2F, UVH, b2, out);
}